// Round 2
// baseline (1321.449 us; speedup 1.0000x reference)
//
#include <hip/hip_runtime.h>
#include <cstdint>

#define NUM_USERS 50000
#define NUM_ITEMS 40000
#define EMB 64
#define NNZ_E 2000000
#define BATCH 1024
#define NCHB 125           // 40000 / 320 col blocks for k_gemm (exact)
#define SLOT_CAP 128       // edges per batch slot (E[40])
#define XCAP 1024          // x nonzeros per row (E[800], sigma 28 -> 8 sigma headroom)
#define INF_I 0x7fffffff

typedef __attribute__((ext_vector_type(8))) short short8;   // 8 x bf16 (4 VGPRs)
typedef __attribute__((ext_vector_type(4))) float float4v;  // MFMA C/D

__device__ __forceinline__ unsigned short f2bf(float f) {
    union { float f; unsigned u; } x; x.f = f;
    unsigned r = x.u + 0x7fffu + ((x.u >> 16) & 1u);
    return (unsigned short)(r >> 16);
}
__device__ __forceinline__ float bf2f(unsigned short s) {
    return __uint_as_float(((unsigned)s) << 16);
}

// ---------------- init: map=INF; cnt/xcnt/scal/compact = 0 ----------------
__global__ __launch_bounds__(256) void k_init(int* __restrict__ map, int* __restrict__ cnt,
                                              float* __restrict__ scal, int2* __restrict__ compact,
                                              int* __restrict__ xcnt) {
    int t = blockIdx.x * blockDim.x + threadIdx.x;
    if (t < NUM_USERS) map[t] = INF_I;
    if (t < BATCH) { cnt[t] = 0; xcnt[t] = 0; }
    if (t < 4) scal[t] = 0.f;
    if (t < BATCH * SLOT_CAP) compact[t] = make_int2(0, 0);   // zero-pad for k_hz unroll
}

__global__ void k_map(const int* __restrict__ user, int* __restrict__ map) {
    int i = blockIdx.x * blockDim.x + threadIdx.x;
    if (i < BATCH) atomicMin(&map[user[i]], i);
}

// ---------------- prep: WqT bf16 transpose | WpBf bf16 cvt ----------------
__global__ __launch_bounds__(256) void k_prep(const float* __restrict__ Wq,
                                              const float* __restrict__ Wp,
                                              unsigned short* __restrict__ WqT,
                                              unsigned short* __restrict__ WpBf) {
    __shared__ float t[128][33];
    const int bid = blockIdx.x;
    const int tid = threadIdx.x;
    if (bid < 1250) {
        const int jb = bid * 32;
        for (int idx = tid; idx < 4096; idx += 256) {
            int d = idx >> 5, c = idx & 31;
            t[d][c] = Wq[(size_t)d * NUM_ITEMS + jb + c];
        }
        __syncthreads();
        for (int idx = tid; idx < 4096; idx += 256) {
            int j = idx >> 7, d = idx & 127;
            WqT[(size_t)(jb + j) * 128 + d] = f2bf(t[d][j]);
        }
    } else {
        const int e0 = ((bid - 1250) * 256 + tid) * 4;
        float4 w = *(const float4*)&Wp[e0];
        ushort4 o;
        o.x = f2bf(w.x); o.y = f2bf(w.y); o.z = f2bf(w.z); o.w = f2bf(w.w);
        *(ushort4*)&WpBf[e0] = o;
    }
}

// ---------------- single-pass scatter into fixed-capacity slot bins ----------------
__global__ __launch_bounds__(256) void k_scatter(const int* __restrict__ rows,
                                                 const int* __restrict__ cols,
                                                 const float* __restrict__ vals,
                                                 const int* __restrict__ map,
                                                 int* __restrict__ cnt,
                                                 int2* __restrict__ compact) {
    const int e = blockIdx.x * 256 + threadIdx.x;
    if (e >= NNZ_E) return;
    int s = map[rows[e]];
    if (s == INF_I) return;
    int pos = atomicAdd(&cnt[s], 1);
    if (pos < SLOT_CAP) compact[s * SLOT_CAP + pos] = make_int2(cols[e], __float_as_int(vals[e]));
}

// ---------------- h + z + KL: 4 waves split edges, ushort2 gathers ----------------
__global__ __launch_bounds__(256) void k_hz(const int* __restrict__ user,
                                            const int* __restrict__ map,
                                            const int* __restrict__ cnt,
                                            const int2* __restrict__ compact,
                                            const unsigned short* __restrict__ WqT,
                                            const float* __restrict__ bq,
                                            const float* __restrict__ eps,
                                            unsigned short* __restrict__ zbBf,
                                            float* __restrict__ zF32,
                                            float* __restrict__ scal) {
    __shared__ float sh[4][128];
    const int i = blockIdx.x;
    const int tid = threadIdx.x;
    const int w = tid >> 6, lane = tid & 63;
    const int u = user[i];
    const int s = map[u];
    const int n8 = (min(cnt[s], SLOT_CAP) + 7) & ~7;   // compact zero-padded -> safe
    const int2* cp = compact + s * SLOT_CAP;
    float ax = 0.f, ay = 0.f;
    for (int e = w; e < n8; e += 8) {
        int2 c0 = cp[e], c1 = cp[e + 4];
        ushort2 w0 = *(const ushort2*)&WqT[(size_t)c0.x * 128 + lane * 2];
        ushort2 w1 = *(const ushort2*)&WqT[(size_t)c1.x * 128 + lane * 2];
        float v0 = __int_as_float(c0.y), v1 = __int_as_float(c1.y);
        ax = fmaf(v0, bf2f(w0.x), ax);
        ay = fmaf(v0, bf2f(w0.y), ay);
        ax = fmaf(v1, bf2f(w1.x), ax);
        ay = fmaf(v1, bf2f(w1.y), ay);
    }
    sh[w][lane * 2] = ax;
    sh[w][lane * 2 + 1] = ay;
    __syncthreads();
    float h = 0.f;
    if (tid < 128) h = sh[0][tid] + sh[1][tid] + sh[2][tid] + sh[3][tid] + bq[tid];
    __syncthreads();
    if (tid < 128) sh[0][tid] = h;
    __syncthreads();
    if (tid < 64) {
        float mu = sh[0][tid];
        float lv = sh[0][tid + 64];
        float z = fmaf(eps[(size_t)u * EMB + tid], __expf(0.5f * lv), mu);
        zbBf[i * EMB + tid] = f2bf(z);
        zF32[i * EMB + tid] = z;
        float kl = 1.0f + lv - mu * mu - __expf(lv);
        #pragma unroll
        for (int o = 32; o; o >>= 1) kl += __shfl_down(kl, o);
        if (tid == 0) atomicAdd(&scal[1], kl);
    }
}

// ---------------- zero the x bins (runs after k_hz frees the WqT alias) ----------------
__global__ __launch_bounds__(256) void k_zero(int2* __restrict__ xlist) {
    int t = blockIdx.x * 256 + threadIdx.x;
    const int stride = gridDim.x * 256;
    for (int i = t; i < BATCH * XCAP; i += stride) xlist[i] = make_int2(0, 0);
}

// ---------------- x binning: pure coalesced stream of x at HBM speed ----------------
// grid (40, BATCH): block streams 256 float4 of one row; per-lane atomic compaction.
__global__ __launch_bounds__(256) void k_xbin(const float* __restrict__ x,
                                              int* __restrict__ xcnt,
                                              int2* __restrict__ xlist) {
    const int row = blockIdx.y;
    const int idx4 = blockIdx.x * 256 + threadIdx.x;
    if (idx4 >= 10000) return;                       // 40000/4 floats4 per row
    const float4 v = ((const float4*)(x + (size_t)row * NUM_ITEMS))[idx4];
    int2* lp = xlist + row * XCAP;
    const int c0 = idx4 * 4;
    if (v.x != 0.f) { int p = atomicAdd(&xcnt[row], 1); if (p < XCAP) lp[p] = make_int2(c0,     __float_as_int(v.x)); }
    if (v.y != 0.f) { int p = atomicAdd(&xcnt[row], 1); if (p < XCAP) lp[p] = make_int2(c0 + 1, __float_as_int(v.y)); }
    if (v.z != 0.f) { int p = atomicAdd(&xcnt[row], 1); if (p < XCAP) lp[p] = make_int2(c0 + 2, __float_as_int(v.z)); }
    if (v.w != 0.f) { int p = atomicAdd(&xcnt[row], 1); if (p < XCAP) lp[p] = make_int2(c0 + 3, __float_as_int(v.w)); }
}

// ---------------- x accumulate: per row, dense loop over binned nonzeros ----------------
// sum_j x_ij*v_ij = z_i.(sum_j x_ij Wp_j) + sum_j x_ij bp_j ; also sum_j x_ij for lse term.
// 4 waves split entries (stride-8, unroll-2 over zero-padded bins); lane owns one dim.
__global__ __launch_bounds__(256) void k_xacc(const int* __restrict__ xcnt,
                                              const int2* __restrict__ xlist,
                                              const float* __restrict__ Wp,
                                              const float* __restrict__ bp,
                                              float* __restrict__ xWp,
                                              float2* __restrict__ rowAux) {
    __shared__ float sacc[4][EMB];
    __shared__ float2 saux[4];
    const int row = blockIdx.x;
    const int tid = threadIdx.x;
    const int w = tid >> 6, lane = tid & 63;
    const int n8 = (min(xcnt[row], XCAP) + 7) & ~7;  // xlist zero-padded -> safe
    const int2* lp = xlist + row * XCAP;
    float acc = 0.f, sx = 0.f, xb = 0.f;
    for (int e = w; e < n8; e += 8) {
        int2 c0 = lp[e], c1 = lp[e + 4];
        float v0 = __int_as_float(c0.y), v1 = __int_as_float(c1.y);
        acc = fmaf(v0, Wp[(size_t)c0.x * EMB + lane], acc);
        acc = fmaf(v1, Wp[(size_t)c1.x * EMB + lane], acc);
        sx += v0 + v1;                                // wave-uniform
        xb = fmaf(v0, bp[c0.x], xb);                  // broadcast load
        xb = fmaf(v1, bp[c1.x], xb);
    }
    sacc[w][lane] = acc;
    if (lane == 0) saux[w] = make_float2(sx, xb);
    __syncthreads();
    if (tid < EMB)
        xWp[(size_t)row * EMB + tid] = sacc[0][tid] + sacc[1][tid] + sacc[2][tid] + sacc[3][tid];
    if (tid == 0)
        rowAux[row] = make_float2(saux[0].x + saux[1].x + saux[2].x + saux[3].x,
                                  saux[0].y + saux[1].y + saux[2].y + saux[3].y);
}

// ---------------- MFMA GEMM: pure LSE (no x) -> per-block (m, s) partials ----------------
// grid (125, 8); 256 thr = 4 waves; wave: 32 rows x 320 cols (5 chunks of 64)
__global__ __launch_bounds__(256) void k_gemm(const unsigned short* __restrict__ zbBf,
                                              const unsigned short* __restrict__ WpBf,
                                              const float* __restrict__ bp,
                                              float2* __restrict__ part) {
    const int tid = threadIdx.x;
    const int wid = tid >> 6, lane = tid & 63;
    const int l15 = lane & 15, quad = lane >> 4;
    const int ibase = blockIdx.y * 128 + wid * 32;

    short8 af[2][2];
    #pragma unroll
    for (int mt = 0; mt < 2; mt++) {
        const unsigned short* pa = zbBf + (size_t)(ibase + mt * 16 + l15) * EMB + quad * 8;
        af[mt][0] = *(const short8*)pa;
        af[mt][1] = *(const short8*)(pa + 32);
    }

    float m_run[2][4], s_run[2][4];
    #pragma unroll
    for (int mt = 0; mt < 2; mt++)
        #pragma unroll
        for (int r = 0; r < 4; r++) { m_run[mt][r] = -1e30f; s_run[mt][r] = 0.f; }

    #pragma unroll
    for (int c5 = 0; c5 < 5; c5++) {
        const int jb = blockIdx.x * 320 + c5 * 64;
        short8 bfr[4][2];
        #pragma unroll
        for (int nt = 0; nt < 4; nt++) {
            const unsigned short* pb = WpBf + (size_t)(jb + nt * 16 + l15) * EMB + quad * 8;
            bfr[nt][0] = *(const short8*)pb;
            bfr[nt][1] = *(const short8*)(pb + 32);
        }
        float4v acc[2][4];
        #pragma unroll
        for (int mt = 0; mt < 2; mt++)
            #pragma unroll
            for (int nt = 0; nt < 4; nt++)
                acc[mt][nt] = (float4v){0.f, 0.f, 0.f, 0.f};
        #pragma unroll
        for (int kh = 0; kh < 2; kh++)
            #pragma unroll
            for (int mt = 0; mt < 2; mt++)
                #pragma unroll
                for (int nt = 0; nt < 4; nt++)
                    acc[mt][nt] = __builtin_amdgcn_mfma_f32_16x16x32_bf16(
                        af[mt][kh], bfr[nt][kh], acc[mt][nt], 0, 0, 0);
        float bpv[4];
        #pragma unroll
        for (int nt = 0; nt < 4; nt++) bpv[nt] = bp[jb + nt * 16 + l15];
        #pragma unroll
        for (int mt = 0; mt < 2; mt++) {
            #pragma unroll
            for (int r = 0; r < 4; r++) {
                float v0 = acc[mt][0][r] + bpv[0];
                float v1 = acc[mt][1][r] + bpv[1];
                float v2 = acc[mt][2][r] + bpv[2];
                float v3 = acc[mt][3][r] + bpv[3];
                float mx = fmaxf(fmaxf(v0, v1), fmaxf(v2, v3));
                float M2 = fmaxf(m_run[mt][r], mx);
                float ls = __expf(v0 - M2) + __expf(v1 - M2) +
                           __expf(v2 - M2) + __expf(v3 - M2);
                s_run[mt][r] = s_run[mt][r] * __expf(m_run[mt][r] - M2) + ls;
                m_run[mt][r] = M2;
            }
        }
    }
    // reduce across the 16 l15 lanes (same rows)
    #pragma unroll
    for (int d = 1; d < 16; d <<= 1) {
        #pragma unroll
        for (int mt = 0; mt < 2; mt++)
            #pragma unroll
            for (int r = 0; r < 4; r++) {
                float m2 = __shfl_xor(m_run[mt][r], d);
                float s2 = __shfl_xor(s_run[mt][r], d);
                float M = fmaxf(m_run[mt][r], m2);
                s_run[mt][r] = s_run[mt][r] * __expf(m_run[mt][r] - M)
                             + s2 * __expf(m2 - M);
                m_run[mt][r] = M;
            }
    }
    if (l15 == 0) {
        #pragma unroll
        for (int mt = 0; mt < 2; mt++)
            #pragma unroll
            for (int r = 0; r < 4; r++) {
                const int gi = ibase + mt * 16 + quad * 4 + r;
                part[(size_t)gi * NCHB + blockIdx.x] =
                    make_float2(m_run[mt][r], s_run[mt][r]);
            }
    }
}

// ---------------- merge: lse per row + z.xWp dot + loss ----------------
__global__ __launch_bounds__(64) void k_merge(const float2* __restrict__ part,
                                              const float* __restrict__ zF32,
                                              const float* __restrict__ xWp,
                                              const float2* __restrict__ rowAux,
                                              float* __restrict__ scal) {
    const int row = blockIdx.x;
    const int lane = threadIdx.x;
    float M = -1e30f, S = 0.f;
    for (int c = lane; c < NCHB; c += 64) {
        float2 p = part[(size_t)row * NCHB + c];
        float M2 = fmaxf(M, p.x);
        S = S * __expf(M - M2) + p.y * __expf(p.x - M2);
        M = M2;
    }
    float d = zF32[(size_t)row * EMB + lane] * xWp[(size_t)row * EMB + lane];
    #pragma unroll
    for (int o = 1; o < 64; o <<= 1) {
        float M2 = __shfl_xor(M, o);
        float S2 = __shfl_xor(S, o);
        float Mn = fmaxf(M, M2);
        S = S * __expf(M - Mn) + S2 * __expf(M2 - Mn);
        M = Mn;
        d += __shfl_xor(d, o);
    }
    if (lane == 0) {
        float2 aux = rowAux[row];
        float lse = M + logf(S);
        float loss = d + aux.y - lse * aux.x;
        atomicAdd(&scal[0], loss);
    }
}

__global__ void k_final(const float* __restrict__ scal, float* __restrict__ out) {
    if (threadIdx.x == 0 && blockIdx.x == 0) {
        out[0] = -scal[0] * (1.0f / BATCH);
        out[1] = -0.5f * scal[1] * (1.0f / BATCH);
    }
}

extern "C" void kernel_launch(void* const* d_in, const int* in_sizes, int n_in,
                              void* d_out, int out_size, void* d_ws, size_t ws_size,
                              hipStream_t stream) {
    const float* graph_vals = (const float*)d_in[0];
    const float* Wq         = (const float*)d_in[1];
    const float* bq         = (const float*)d_in[2];
    const float* Wp         = (const float*)d_in[3];
    const float* bp         = (const float*)d_in[4];
    const float* x          = (const float*)d_in[5];
    const float* eps        = (const float*)d_in[6];
    const int*   graph_rows = (const int*)d_in[7];
    const int*   graph_cols = (const int*)d_in[8];
    const int*   user       = (const int*)d_in[9];
    float* out = (float*)d_out;

    char* ws = (char*)d_ws;
    int*            map     = (int*)(ws + 0);                    //   200,704
    int*            cnt     = (int*)(ws + 200704);               //     4,096
    float*          scal    = (float*)(ws + 204800);             //       256
    int2*           compact = (int2*)(ws + 205056);              // 1,048,576 -> 1,253,632
    unsigned short* zbBf    = (unsigned short*)(ws + 1253632);   //   131,072 -> 1,384,704
    float*          zF32    = (float*)(ws + 1384704);            //   262,144 -> 1,646,848
    float*          xWp     = (float*)(ws + 1646848);            //   262,144 -> 1,908,992
    float2*         rowAux  = (float2*)(ws + 1908992);           //     8,192 -> 1,917,184
    float2*         part    = (float2*)(ws + 1917184);           // 1,024,000 -> 2,941,184
    unsigned short* WpBf    = (unsigned short*)(ws + 2941184);   // 5,120,000 -> 8,061,184
    unsigned short* WqT     = (unsigned short*)(ws + 8061184);   // 10,240,000 -> 18,301,184
    // xlist ALIASES WqT: WqT is dead after k_hz; k_zero/k_xbin run strictly later in-stream.
    int2*           xlist   = (int2*)(ws + 8061184);             // 8,388,608 (within WqT region)
    int*            xcnt    = (int*)(ws + 18301184);             //     4,096 -> 18,305,280

    k_init<<<512, 256, 0, stream>>>(map, cnt, scal, compact, xcnt);
    k_map<<<4, 256, 0, stream>>>(user, map);
    k_prep<<<3750, 256, 0, stream>>>(Wq, Wp, WqT, WpBf);
    k_scatter<<<7813, 256, 0, stream>>>(graph_rows, graph_cols, graph_vals, map, cnt, compact);
    k_hz<<<BATCH, 256, 0, stream>>>(user, map, cnt, compact, WqT, bq, eps, zbBf, zF32, scal);
    k_zero<<<1024, 256, 0, stream>>>(xlist);
    dim3 gx(40, BATCH);
    k_xbin<<<gx, 256, 0, stream>>>(x, xcnt, xlist);
    k_xacc<<<BATCH, 256, 0, stream>>>(xcnt, xlist, Wp, bp, xWp, rowAux);
    dim3 g(NCHB, BATCH / 128);
    k_gemm<<<g, 256, 0, stream>>>(zbBf, WpBf, bp, part);
    k_merge<<<BATCH, 64, 0, stream>>>(part, zF32, xWp, rowAux, scal);
    k_final<<<1, 64, 0, stream>>>(scal, out);
}

// Round 3
// 384.982 us; speedup vs baseline: 3.4325x; 3.4325x over previous
//
#include <hip/hip_runtime.h>
#include <cstdint>

#define NUM_USERS 50000
#define NUM_ITEMS 40000
#define EMB 64
#define NNZ_E 2000000
#define BATCH 1024
#define NCHB 125           // 40000 / 320 col blocks for k_gemm and k_x (exact)
#define SLOT_CAP 128       // edges per batch slot (E[40])
#define INF_I 0x7fffffff

typedef __attribute__((ext_vector_type(8))) short short8;   // 8 x bf16 (4 VGPRs)
typedef __attribute__((ext_vector_type(4))) float float4v;  // MFMA C/D

__device__ __forceinline__ unsigned short f2bf(float f) {
    union { float f; unsigned u; } x; x.f = f;
    unsigned r = x.u + 0x7fffu + ((x.u >> 16) & 1u);
    return (unsigned short)(r >> 16);
}
__device__ __forceinline__ float bf2f(unsigned short s) {
    return __uint_as_float(((unsigned)s) << 16);
}

// ---------------- init: map=INF; cnt/scal/compact = 0 ----------------
__global__ __launch_bounds__(256) void k_init(int* __restrict__ map, int* __restrict__ cnt,
                                              float* __restrict__ scal, int2* __restrict__ compact) {
    int t = blockIdx.x * blockDim.x + threadIdx.x;
    if (t < NUM_USERS) map[t] = INF_I;
    if (t < BATCH) cnt[t] = 0;
    if (t < 4) scal[t] = 0.f;
    if (t < BATCH * SLOT_CAP) compact[t] = make_int2(0, 0);   // zero-pad for k_hz unroll
}

__global__ void k_map(const int* __restrict__ user, int* __restrict__ map) {
    int i = blockIdx.x * blockDim.x + threadIdx.x;
    if (i < BATCH) atomicMin(&map[user[i]], i);
}

// ---------------- prep: WqT transpose | WpBf cvt | WpT transpose | bpBf cvt ----------------
__global__ __launch_bounds__(256) void k_prep(const float* __restrict__ Wq,
                                              const float* __restrict__ Wp,
                                              const float* __restrict__ bp,
                                              unsigned short* __restrict__ WqT,
                                              unsigned short* __restrict__ WpBf,
                                              unsigned short* __restrict__ WpT,
                                              unsigned short* __restrict__ bpBf) {
    __shared__ float t2f[160 * 65];     // shared by both transpose branches
    const int bid = blockIdx.x;
    const int tid = threadIdx.x;
    if (bid < 1250) {                   // WqT: (128 x 40000) -> (40000 x 128) bf16
        const int jb = bid * 32;
        for (int idx = tid; idx < 4096; idx += 256) {
            int d = idx >> 5, c = idx & 31;
            t2f[d * 33 + c] = Wq[(size_t)d * NUM_ITEMS + jb + c];
        }
        __syncthreads();
        for (int idx = tid; idx < 4096; idx += 256) {
            int j = idx >> 7, d = idx & 127;
            WqT[(size_t)(jb + j) * 128 + d] = f2bf(t2f[d * 33 + j]);
        }
    } else if (bid < 3750) {            // WpBf: row-major bf16 copy of Wp
        const int e0 = ((bid - 1250) * 256 + tid) * 4;
        float4 w = *(const float4*)&Wp[e0];
        ushort4 o;
        o.x = f2bf(w.x); o.y = f2bf(w.y); o.z = f2bf(w.z); o.w = f2bf(w.w);
        *(ushort4*)&WpBf[e0] = o;
    } else if (bid < 4000) {            // WpT: (40000 x 64) -> (64 x 40000) bf16
        const int j0 = (bid - 3750) * 160;
        for (int idx = tid; idx < 10240; idx += 256) {
            int jl = idx >> 6, d = idx & 63;
            t2f[jl * 65 + d] = Wp[(size_t)(j0 + jl) * 64 + d];
        }
        __syncthreads();
        for (int idx = tid; idx < 10240; idx += 256) {
            int d = idx / 160, jl = idx - d * 160;
            WpT[(size_t)d * NUM_ITEMS + j0 + jl] = f2bf(t2f[jl * 65 + d]);
        }
    } else {                            // bpBf: bf16 copy of bp
        const int e0 = ((bid - 4000) * 256 + tid) * 4;
        if (e0 < NUM_ITEMS) {
            float4 w = *(const float4*)&bp[e0];
            ushort4 o;
            o.x = f2bf(w.x); o.y = f2bf(w.y); o.z = f2bf(w.z); o.w = f2bf(w.w);
            *(ushort4*)&bpBf[e0] = o;
        }
    }
}

// ---------------- single-pass scatter into fixed-capacity slot bins ----------------
__global__ __launch_bounds__(256) void k_scatter(const int* __restrict__ rows,
                                                 const int* __restrict__ cols,
                                                 const float* __restrict__ vals,
                                                 const int* __restrict__ map,
                                                 int* __restrict__ cnt,
                                                 int2* __restrict__ compact) {
    const int e = blockIdx.x * 256 + threadIdx.x;
    if (e >= NNZ_E) return;
    int s = map[rows[e]];
    if (s == INF_I) return;
    int pos = atomicAdd(&cnt[s], 1);
    if (pos < SLOT_CAP) compact[s * SLOT_CAP + pos] = make_int2(cols[e], __float_as_int(vals[e]));
}

// ---------------- h + z + KL: 4 waves split edges, ushort2 gathers ----------------
__global__ __launch_bounds__(256) void k_hz(const int* __restrict__ user,
                                            const int* __restrict__ map,
                                            const int* __restrict__ cnt,
                                            const int2* __restrict__ compact,
                                            const unsigned short* __restrict__ WqT,
                                            const float* __restrict__ bq,
                                            const float* __restrict__ eps,
                                            unsigned short* __restrict__ zbBf,
                                            float* __restrict__ zF32,
                                            float* __restrict__ scal) {
    __shared__ float sh[4][128];
    const int i = blockIdx.x;
    const int tid = threadIdx.x;
    const int w = tid >> 6, lane = tid & 63;
    const int u = user[i];
    const int s = map[u];
    const int n8 = (min(cnt[s], SLOT_CAP) + 7) & ~7;   // compact zero-padded -> safe
    const int2* cp = compact + s * SLOT_CAP;
    float ax = 0.f, ay = 0.f;
    for (int e = w; e < n8; e += 8) {
        int2 c0 = cp[e], c1 = cp[e + 4];
        ushort2 w0 = *(const ushort2*)&WqT[(size_t)c0.x * 128 + lane * 2];
        ushort2 w1 = *(const ushort2*)&WqT[(size_t)c1.x * 128 + lane * 2];
        float v0 = __int_as_float(c0.y), v1 = __int_as_float(c1.y);
        ax = fmaf(v0, bf2f(w0.x), ax);
        ay = fmaf(v0, bf2f(w0.y), ay);
        ax = fmaf(v1, bf2f(w1.x), ax);
        ay = fmaf(v1, bf2f(w1.y), ay);
    }
    sh[w][lane * 2] = ax;
    sh[w][lane * 2 + 1] = ay;
    __syncthreads();
    float h = 0.f;
    if (tid < 128) h = sh[0][tid] + sh[1][tid] + sh[2][tid] + sh[3][tid] + bq[tid];
    __syncthreads();
    if (tid < 128) sh[0][tid] = h;
    __syncthreads();
    if (tid < 64) {
        float mu = sh[0][tid];
        float lv = sh[0][tid + 64];
        float z = fmaf(eps[(size_t)u * EMB + tid], __expf(0.5f * lv), mu);
        zbBf[i * EMB + tid] = f2bf(z);
        zF32[i * EMB + tid] = z;
        float kl = 1.0f + lv - mu * mu - __expf(lv);
        #pragma unroll
        for (int o = 32; o; o >>= 1) kl += __shfl_down(kl, o);
        if (tid == 0) atomicAdd(&scal[1], kl);
    }
}

// ---------------- x-term as dense MFMA GEMM: X @ [Wp | bp | ones] ----------------
// x in {0,1} -> exact in bf16. Per (kc,row): dx = z . (X@Wp), sx = X@1, xb = X@bp.
// grid (125, 8); block = 4 waves x 32 rows; K-chunk = 320 items (10 steps of 32).
// x streamed once, fully coalesced (128B/row segments); WpT/bpBf are L2-resident.
__global__ __launch_bounds__(256) void k_x(const float* __restrict__ x,
                                           const unsigned short* __restrict__ WpT,
                                           const unsigned short* __restrict__ bpBf,
                                           const float* __restrict__ zF32,
                                           float4* __restrict__ aux4) {
    const int tid = threadIdx.x;
    const int wid = tid >> 6, lane = tid & 63;
    const int l15 = lane & 15, quad = lane >> 4;
    const int kc = blockIdx.x;
    const int ibase = blockIdx.y * 128 + wid * 32;

    float4v acc[2][4], accA[2];
    #pragma unroll
    for (int mt = 0; mt < 2; mt++) {
        accA[mt] = (float4v){0.f, 0.f, 0.f, 0.f};
        #pragma unroll
        for (int nt = 0; nt < 4; nt++) acc[mt][nt] = (float4v){0.f, 0.f, 0.f, 0.f};
    }

    #pragma unroll
    for (int st = 0; st < 10; st++) {
        const int kb = kc * 320 + st * 32;
        short8 af[2];
        #pragma unroll
        for (int mt = 0; mt < 2; mt++) {
            const float* px = x + (size_t)(ibase + mt * 16 + l15) * NUM_ITEMS + kb + quad * 8;
            float4 a0 = *(const float4*)px;
            float4 a1 = *(const float4*)(px + 4);
            short8 v;
            v[0] = (short)f2bf(a0.x); v[1] = (short)f2bf(a0.y);
            v[2] = (short)f2bf(a0.z); v[3] = (short)f2bf(a0.w);
            v[4] = (short)f2bf(a1.x); v[5] = (short)f2bf(a1.y);
            v[6] = (short)f2bf(a1.z); v[7] = (short)f2bf(a1.w);
            af[mt] = v;
        }
        short8 bfr[4];
        #pragma unroll
        for (int nt = 0; nt < 4; nt++)
            bfr[nt] = *(const short8*)&WpT[(size_t)(nt * 16 + l15) * NUM_ITEMS + kb + quad * 8];
        short8 ab;
        if (l15 == 0) {
            ab = *(const short8*)&bpBf[kb + quad * 8];
        } else if (l15 == 1) {
            short o = (short)0x3F80;                 // bf16 1.0
            ab = (short8){o, o, o, o, o, o, o, o};
        } else {
            ab = (short8){0, 0, 0, 0, 0, 0, 0, 0};
        }
        #pragma unroll
        for (int mt = 0; mt < 2; mt++) {
            #pragma unroll
            for (int nt = 0; nt < 4; nt++)
                acc[mt][nt] = __builtin_amdgcn_mfma_f32_16x16x32_bf16(
                    af[mt], bfr[nt], acc[mt][nt], 0, 0, 0);
            accA[mt] = __builtin_amdgcn_mfma_f32_16x16x32_bf16(
                    af[mt], ab, accA[mt], 0, 0, 0);
        }
    }
    // fold partial Y into dx = z . Y (per row), extract sx (ones col) / xb (bp col)
    #pragma unroll
    for (int mt = 0; mt < 2; mt++) {
        #pragma unroll
        for (int r = 0; r < 4; r++) {
            const int row = ibase + mt * 16 + quad * 4 + r;
            float dxp = 0.f;
            #pragma unroll
            for (int nt = 0; nt < 4; nt++)
                dxp += zF32[(size_t)row * EMB + nt * 16 + l15] * acc[mt][nt][r];
            #pragma unroll
            for (int d = 1; d < 16; d <<= 1) dxp += __shfl_xor(dxp, d);
            float sxv = __shfl(accA[mt][r], (lane & 48) + 1);   // col 1 = ones
            if (l15 == 0)
                aux4[(size_t)kc * BATCH + row] = make_float4(dxp, sxv, accA[mt][r], 0.f);
        }
    }
}

// ---------------- MFMA GEMM: pure LSE (no x) -> per-block (m, s) partials ----------------
// grid (125, 8); 256 thr = 4 waves; wave: 32 rows x 320 cols (5 chunks of 64)
__global__ __launch_bounds__(256) void k_gemm(const unsigned short* __restrict__ zbBf,
                                              const unsigned short* __restrict__ WpBf,
                                              const float* __restrict__ bp,
                                              float2* __restrict__ part) {
    const int tid = threadIdx.x;
    const int wid = tid >> 6, lane = tid & 63;
    const int l15 = lane & 15, quad = lane >> 4;
    const int ibase = blockIdx.y * 128 + wid * 32;

    short8 af[2][2];
    #pragma unroll
    for (int mt = 0; mt < 2; mt++) {
        const unsigned short* pa = zbBf + (size_t)(ibase + mt * 16 + l15) * EMB + quad * 8;
        af[mt][0] = *(const short8*)pa;
        af[mt][1] = *(const short8*)(pa + 32);
    }

    float m_run[2][4], s_run[2][4];
    #pragma unroll
    for (int mt = 0; mt < 2; mt++)
        #pragma unroll
        for (int r = 0; r < 4; r++) { m_run[mt][r] = -1e30f; s_run[mt][r] = 0.f; }

    #pragma unroll
    for (int c5 = 0; c5 < 5; c5++) {
        const int jb = blockIdx.x * 320 + c5 * 64;
        short8 bfr[4][2];
        #pragma unroll
        for (int nt = 0; nt < 4; nt++) {
            const unsigned short* pb = WpBf + (size_t)(jb + nt * 16 + l15) * EMB + quad * 8;
            bfr[nt][0] = *(const short8*)pb;
            bfr[nt][1] = *(const short8*)(pb + 32);
        }
        float4v acc[2][4];
        #pragma unroll
        for (int mt = 0; mt < 2; mt++)
            #pragma unroll
            for (int nt = 0; nt < 4; nt++)
                acc[mt][nt] = (float4v){0.f, 0.f, 0.f, 0.f};
        #pragma unroll
        for (int kh = 0; kh < 2; kh++)
            #pragma unroll
            for (int mt = 0; mt < 2; mt++)
                #pragma unroll
                for (int nt = 0; nt < 4; nt++)
                    acc[mt][nt] = __builtin_amdgcn_mfma_f32_16x16x32_bf16(
                        af[mt][kh], bfr[nt][kh], acc[mt][nt], 0, 0, 0);
        float bpv[4];
        #pragma unroll
        for (int nt = 0; nt < 4; nt++) bpv[nt] = bp[jb + nt * 16 + l15];
        #pragma unroll
        for (int mt = 0; mt < 2; mt++) {
            #pragma unroll
            for (int r = 0; r < 4; r++) {
                float v0 = acc[mt][0][r] + bpv[0];
                float v1 = acc[mt][1][r] + bpv[1];
                float v2 = acc[mt][2][r] + bpv[2];
                float v3 = acc[mt][3][r] + bpv[3];
                float mx = fmaxf(fmaxf(v0, v1), fmaxf(v2, v3));
                float M2 = fmaxf(m_run[mt][r], mx);
                float ls = __expf(v0 - M2) + __expf(v1 - M2) +
                           __expf(v2 - M2) + __expf(v3 - M2);
                s_run[mt][r] = s_run[mt][r] * __expf(m_run[mt][r] - M2) + ls;
                m_run[mt][r] = M2;
            }
        }
    }
    // reduce across the 16 l15 lanes (same rows)
    #pragma unroll
    for (int d = 1; d < 16; d <<= 1) {
        #pragma unroll
        for (int mt = 0; mt < 2; mt++)
            #pragma unroll
            for (int r = 0; r < 4; r++) {
                float m2 = __shfl_xor(m_run[mt][r], d);
                float s2 = __shfl_xor(s_run[mt][r], d);
                float M = fmaxf(m_run[mt][r], m2);
                s_run[mt][r] = s_run[mt][r] * __expf(m_run[mt][r] - M)
                             + s2 * __expf(m2 - M);
                m_run[mt][r] = M;
            }
    }
    if (l15 == 0) {
        #pragma unroll
        for (int mt = 0; mt < 2; mt++)
            #pragma unroll
            for (int r = 0; r < 4; r++) {
                const int gi = ibase + mt * 16 + quad * 4 + r;
                part[(size_t)gi * NCHB + blockIdx.x] =
                    make_float2(m_run[mt][r], s_run[mt][r]);
            }
    }
}

// ---------------- merge: lse per row + dx/sx/xb partial sums + loss ----------------
__global__ __launch_bounds__(64) void k_merge(const float2* __restrict__ part,
                                              const float4* __restrict__ aux4,
                                              float* __restrict__ scal) {
    const int row = blockIdx.x;
    const int lane = threadIdx.x;
    float M = -1e30f, S = 0.f, dx = 0.f, sx = 0.f, xb = 0.f;
    for (int c = lane; c < NCHB; c += 64) {
        float2 p = part[(size_t)row * NCHB + c];
        float M2 = fmaxf(M, p.x);
        S = S * __expf(M - M2) + p.y * __expf(p.x - M2);
        M = M2;
        float4 a = aux4[(size_t)c * BATCH + row];
        dx += a.x; sx += a.y; xb += a.z;
    }
    #pragma unroll
    for (int o = 1; o < 64; o <<= 1) {
        float M2 = __shfl_xor(M, o);
        float S2 = __shfl_xor(S, o);
        float Mn = fmaxf(M, M2);
        S = S * __expf(M - Mn) + S2 * __expf(M2 - Mn);
        M = Mn;
        dx += __shfl_xor(dx, o);
        sx += __shfl_xor(sx, o);
        xb += __shfl_xor(xb, o);
    }
    if (lane == 0) {
        float lse = M + logf(S);
        float loss = dx + xb - lse * sx;
        atomicAdd(&scal[0], loss);
    }
}

__global__ void k_final(const float* __restrict__ scal, float* __restrict__ out) {
    if (threadIdx.x == 0 && blockIdx.x == 0) {
        out[0] = -scal[0] * (1.0f / BATCH);
        out[1] = -0.5f * scal[1] * (1.0f / BATCH);
    }
}

extern "C" void kernel_launch(void* const* d_in, const int* in_sizes, int n_in,
                              void* d_out, int out_size, void* d_ws, size_t ws_size,
                              hipStream_t stream) {
    const float* graph_vals = (const float*)d_in[0];
    const float* Wq         = (const float*)d_in[1];
    const float* bq         = (const float*)d_in[2];
    const float* Wp         = (const float*)d_in[3];
    const float* bp         = (const float*)d_in[4];
    const float* x          = (const float*)d_in[5];
    const float* eps        = (const float*)d_in[6];
    const int*   graph_rows = (const int*)d_in[7];
    const int*   graph_cols = (const int*)d_in[8];
    const int*   user       = (const int*)d_in[9];
    float* out = (float*)d_out;

    char* ws = (char*)d_ws;
    int*            map     = (int*)(ws + 0);                    //   200,704
    int*            cnt     = (int*)(ws + 200704);               //     4,096
    float*          scal    = (float*)(ws + 204800);             //       256
    int2*           compact = (int2*)(ws + 205056);              // 1,048,576 -> 1,253,632
    unsigned short* zbBf    = (unsigned short*)(ws + 1253632);   //   131,072 -> 1,384,704
    float*          zF32    = (float*)(ws + 1384704);            //   262,144 -> 1,646,848
    float2*         part    = (float2*)(ws + 1646848);           // 1,024,000 -> 2,670,848
    unsigned short* WpBf    = (unsigned short*)(ws + 2670848);   // 5,120,000 -> 7,790,848
    unsigned short* WqT     = (unsigned short*)(ws + 7790848);   // 10,240,000 -> 18,030,848
    unsigned short* WpT     = (unsigned short*)(ws + 18030848);  // 5,120,000 -> 23,150,848
    unsigned short* bpBf    = (unsigned short*)(ws + 23150848);  //    80,000 -> 23,230,848
    float4*         aux4    = (float4*)(ws + 23230848);          // 2,048,000 -> 25,278,848

    k_init<<<512, 256, 0, stream>>>(map, cnt, scal, compact);
    k_map<<<4, 256, 0, stream>>>(user, map);
    k_prep<<<4040, 256, 0, stream>>>(Wq, Wp, bp, WqT, WpBf, WpT, bpBf);
    k_scatter<<<7813, 256, 0, stream>>>(graph_rows, graph_cols, graph_vals, map, cnt, compact);
    k_hz<<<BATCH, 256, 0, stream>>>(user, map, cnt, compact, WqT, bq, eps, zbBf, zF32, scal);
    dim3 g(NCHB, BATCH / 128);
    k_x<<<g, 256, 0, stream>>>(x, WpT, bpBf, zF32, aux4);
    k_gemm<<<g, 256, 0, stream>>>(zbBf, WpBf, bp, part);
    k_merge<<<BATCH, 64, 0, stream>>>(part, aux4, scal);
    k_final<<<1, 64, 0, stream>>>(scal, out);
}